// Round 7
// baseline (248.132 us; speedup 1.0000x reference)
//
#include <hip/hip_runtime.h>

#define IN1 64
#define MID 128
#define OUT2 8
#define YPAD 136

__device__ __forceinline__ unsigned short f2bf(float f) {
    unsigned int u = __float_as_uint(f);
    unsigned int r = (u + 0x7fff + ((u >> 16) & 1)) >> 16;  // RNE
    return (unsigned short)r;
}

// ---------------- CSR build ----------------

__global__ void k_count(const int* __restrict__ dst, int* __restrict__ deg_i, int E2, int E) {
    int gid = blockIdx.x * blockDim.x + threadIdx.x;
    if (gid < E2) {
        int2 d = ((const int2*)dst)[gid];
        atomicAdd(&deg_i[d.x], 1);
        atomicAdd(&deg_i[d.y], 1);
    }
    if (gid == 0 && (E & 1)) atomicAdd(&deg_i[dst[E - 1]], 1);
}

// One kernel: deg -> dinv, block-local scan, cross-block prefix via
// publish + device-scope spin (all G<=256 blocks co-resident), cursor,
// and bf16 prescale of x into xb. Replaces bsum/scanb/rowptr/prescale.
__global__ __launch_bounds__(256) void k_scan_fused(const int* __restrict__ deg_i,
                                                    const float* __restrict__ x,
                                                    int* __restrict__ cursor,
                                                    float* __restrict__ dinv,
                                                    unsigned short* __restrict__ xb,
                                                    int* __restrict__ bsum,
                                                    int* __restrict__ done,
                                                    int n, int G) {
    __shared__ int wsum[4];
    __shared__ int wps[4];
    __shared__ float dloc[256];

    int t = threadIdx.x, b = blockIdx.x, i = b * 256 + t;
    int lane = t & 63, wid = t >> 6;

    int v = (i < n) ? deg_i[i] : 0;
    float di = rsqrtf((float)(v + 1));
    if (i < n) dinv[i] = di;
    dloc[t] = di;

    // wave-inclusive scan
    int s = v;
#pragma unroll
    for (int off = 1; off < 64; off <<= 1) {
        int u = __shfl_up(s, off, 64);
        if (lane >= off) s += u;
    }
    if (lane == 63) wsum[wid] = s;
    __syncthreads();
    int wprefix = 0;
    for (int w = 0; w < wid; ++w) wprefix += wsum[w];

    // publish block total, signal
    if (t == 0) {
        int tot = wsum[0] + wsum[1] + wsum[2] + wsum[3];
        __hip_atomic_store(&bsum[b], tot, __ATOMIC_RELEASE, __HIP_MEMORY_SCOPE_AGENT);
        __hip_atomic_fetch_add(done, 1, __ATOMIC_RELEASE, __HIP_MEMORY_SCOPE_AGENT);
    }

    // overlap: bf16 prescale of this block's 256 rows (16 float4 / thread)
    {
        const float4* x4 = (const float4*)x;
        int base4 = b * 4096;  // 256 rows * 16 float4
        int lim4 = n * 16;
#pragma unroll 4
        for (int q = t; q < 4096; q += 256) {
            int g4 = base4 + q;
            if (g4 < lim4) {
                float d = dloc[q >> 4];
                float4 vx = x4[g4];
                ushort4 p;
                p.x = f2bf(vx.x * d); p.y = f2bf(vx.y * d);
                p.z = f2bf(vx.z * d); p.w = f2bf(vx.w * d);
                ((ushort4*)xb)[g4] = p;
            }
        }
    }

    // wait for all block totals
    if (t == 0) {
        while (__hip_atomic_load(done, __ATOMIC_ACQUIRE, __HIP_MEMORY_SCOPE_AGENT) < G) {}
    }
    __syncthreads();

    // blockbase = sum of bsum[0..b-1]
    int pv = (t < b) ? __hip_atomic_load(&bsum[t], __ATOMIC_ACQUIRE, __HIP_MEMORY_SCOPE_AGENT) : 0;
    int ps = pv;
#pragma unroll
    for (int off = 1; off < 64; off <<= 1) ps += __shfl_xor(ps, off, 64);
    if (lane == 0) wps[wid] = ps;
    __syncthreads();
    int blockbase = wps[0] + wps[1] + wps[2] + wps[3];

    if (i < n) cursor[i] = (s - v) + wprefix + blockbase;
}

// col[p]=src via cursor atomics; afterwards cursor[d] = row end
__global__ void k_fill(const int* __restrict__ src, const int* __restrict__ dst,
                       int* __restrict__ cursor, int* __restrict__ col, int E2, int E) {
    int gid = blockIdx.x * blockDim.x + threadIdx.x;
    if (gid < E2) {
        int2 s = ((const int2*)src)[gid];
        int2 d = ((const int2*)dst)[gid];
        int p0 = atomicAdd(&cursor[d.x], 1);
        col[p0] = s.x;
        int p1 = atomicAdd(&cursor[d.y], 1);
        col[p1] = s.y;
    }
    if (gid == 0 && (E & 1)) {
        int p = atomicAdd(&cursor[dst[E - 1]], 1);
        col[p] = src[E - 1];
    }
}

// ---------------- fused layer1: bf16 gather + 64->128->8 MLP ----------------
// One wave = 4 nodes; block = 4 waves. xb rows are bf16, prescaled by dinv.
// Lanes 0-31 = neighbor stream A, 32-63 = stream B; each lane: 2 feats (1 uint).
__global__ __launch_bounds__(256) void k_node(const unsigned int* __restrict__ xbu,
                                              const int* __restrict__ deg_i,
                                              const int* __restrict__ cursor,
                                              const int* __restrict__ col,
                                              const float* __restrict__ dinv,
                                              const float* __restrict__ W1,
                                              const float* __restrict__ b1,
                                              const float* __restrict__ W2,
                                              float* __restrict__ z, int n) {
    __shared__ float w2s[MID * OUT2];   // [k][c]
    __shared__ float tS[4][4][IN1];     // wave-private
    __shared__ float yS[4][4][YPAD];    // wave-private

    int t = threadIdx.x;
    ((float4*)w2s)[t] = ((const float4*)W2)[t];

    int lane = t & 63, wave = t >> 6;
    int half = lane >> 5;
    int fl = lane & 31;
    int lane16 = lane & 15;
    int row0 = blockIdx.x * 16 + wave * 4;

    // ---- phase A: gather (pure sums of prescaled bf16 rows) ----
#pragma unroll
    for (int nd = 0; nd < 4; ++nd) {
        int row = row0 + nd;
        float ax = 0.0f, ay = 0.0f;
        if (row < n) {
            if (half == 0) {  // self-loop
                unsigned int u = xbu[(size_t)row * 32 + fl];
                ax = __uint_as_float(u << 16);
                ay = __uint_as_float(u & 0xffff0000u);
            }
            int end = cursor[row];
            int j = end - deg_i[row];
            for (; j + 16 <= end; j += 16) {
                int cv = col[j + lane16];
#pragma unroll
                for (int p = 0; p < 8; ++p) {
                    int s = __shfl(cv, 2 * p + half, 64);
                    unsigned int u = xbu[(size_t)s * 32 + fl];
                    ax += __uint_as_float(u << 16);
                    ay += __uint_as_float(u & 0xffff0000u);
                }
            }
            int rem = end - j;
            if (rem > 0) {
                int cv = (lane16 < rem) ? col[j + lane16] : 0;
#pragma unroll
                for (int p = 0; p < 8; ++p) {
                    int idx = 2 * p + half;
                    int s = __shfl(cv, idx, 64);
                    unsigned int u = xbu[(size_t)s * 32 + fl];
                    if (idx < rem) {
                        ax += __uint_as_float(u << 16);
                        ay += __uint_as_float(u & 0xffff0000u);
                    }
                }
            }
        }
        ax += __shfl_xor(ax, 32, 64);
        ay += __shfl_xor(ay, 32, 64);
        if (half == 0) {
            float2 w = {ax, ay};
            *(float2*)&tS[wave][nd][2 * fl] = w;
        }
    }
    // no barrier: tS wave-private

    float dnd[4];
#pragma unroll
    for (int k = 0; k < 4; ++k) dnd[k] = dinv[min(row0 + k, n - 1)];

    // ---- phase B: y = relu(di * (g @ W1) + b1) ----
    float ya0 = 0.f, yb0 = 0.f, ya1 = 0.f, yb1 = 0.f;
    float ya2 = 0.f, yb2 = 0.f, ya3 = 0.f, yb3 = 0.f;
#pragma unroll 4
    for (int k4 = 0; k4 < IN1; k4 += 4) {
        float4 t0 = *(const float4*)&tS[wave][0][k4];
        float4 t1 = *(const float4*)&tS[wave][1][k4];
        float4 t2 = *(const float4*)&tS[wave][2][k4];
        float4 t3 = *(const float4*)&tS[wave][3][k4];
#pragma unroll
        for (int kk = 0; kk < 4; ++kk) {
            int k = k4 + kk;
            float wa = W1[k * MID + lane];
            float wb = W1[k * MID + lane + 64];
            float e0 = (&t0.x)[kk], e1 = (&t1.x)[kk], e2 = (&t2.x)[kk], e3 = (&t3.x)[kk];
            ya0 = fmaf(e0, wa, ya0); yb0 = fmaf(e0, wb, yb0);
            ya1 = fmaf(e1, wa, ya1); yb1 = fmaf(e1, wb, yb1);
            ya2 = fmaf(e2, wa, ya2); yb2 = fmaf(e2, wb, yb2);
            ya3 = fmaf(e3, wa, ya3); yb3 = fmaf(e3, wb, yb3);
        }
    }
    float bl = b1[lane], bh = b1[lane + 64];
    yS[wave][0][lane] = fmaxf(fmaf(ya0, dnd[0], bl), 0.f);
    yS[wave][0][lane + 64] = fmaxf(fmaf(yb0, dnd[0], bh), 0.f);
    yS[wave][1][lane] = fmaxf(fmaf(ya1, dnd[1], bl), 0.f);
    yS[wave][1][lane + 64] = fmaxf(fmaf(yb1, dnd[1], bh), 0.f);
    yS[wave][2][lane] = fmaxf(fmaf(ya2, dnd[2], bl), 0.f);
    yS[wave][2][lane + 64] = fmaxf(fmaf(yb2, dnd[2], bh), 0.f);
    yS[wave][3][lane] = fmaxf(fmaf(ya3, dnd[3], bl), 0.f);
    yS[wave][3][lane + 64] = fmaxf(fmaf(yb3, dnd[3], bh), 0.f);

    __syncthreads();  // w2s visibility only

    // ---- phase C: z = di * (y @ W2) ----
    int nd2 = lane >> 4, ch = lane & 15;
    float p[OUT2];
#pragma unroll
    for (int c = 0; c < OUT2; ++c) p[c] = 0.0f;
#pragma unroll
    for (int kk = 0; kk < 8; ++kk) {
        int k = kk * 16 + ch;
        float yk = yS[wave][nd2][k];
        float4 wlo = *(const float4*)&w2s[k * OUT2];
        float4 whi = *(const float4*)&w2s[k * OUT2 + 4];
        p[0] = fmaf(yk, wlo.x, p[0]); p[1] = fmaf(yk, wlo.y, p[1]);
        p[2] = fmaf(yk, wlo.z, p[2]); p[3] = fmaf(yk, wlo.w, p[3]);
        p[4] = fmaf(yk, whi.x, p[4]); p[5] = fmaf(yk, whi.y, p[5]);
        p[6] = fmaf(yk, whi.z, p[6]); p[7] = fmaf(yk, whi.w, p[7]);
    }
#pragma unroll
    for (int off = 1; off < 16; off <<= 1) {
#pragma unroll
        for (int c = 0; c < OUT2; ++c) p[c] += __shfl_xor(p[c], off, 64);
    }
    int row = row0 + nd2;
    if (row < n && ch < OUT2) {
        z[(size_t)row * OUT2 + ch] = p[ch] * dinv[row];
    }
}

// ---------------- layer2 gather ----------------
__global__ __launch_bounds__(256) void k_gather2(const int* __restrict__ deg_i,
                                                 const int* __restrict__ cursor,
                                                 const int* __restrict__ col,
                                                 const float* __restrict__ z,
                                                 const float* __restrict__ dinv,
                                                 const float* __restrict__ b2,
                                                 float* __restrict__ out, int n) {
    int t = threadIdx.x, lane = t & 63, wave = t >> 6;
    int node = blockIdx.x * 4 + wave;
    if (node >= n) return;
    int nb = lane >> 3, c = lane & 7;
    float acc = (nb == 0) ? z[(size_t)node * OUT2 + c] : 0.0f;  // self-loop
    int end = cursor[node];
    int j = end - deg_i[node] + nb;
    for (; j + 8 < end; j += 16) {
        int s0 = col[j], s1 = col[j + 8];
        float a0 = z[(size_t)s0 * OUT2 + c];
        float a1 = z[(size_t)s1 * OUT2 + c];
        acc += a0 + a1;
    }
    if (j < end) acc += z[(size_t)col[j] * OUT2 + c];
#pragma unroll
    for (int off = 8; off < 64; off <<= 1) acc += __shfl_xor(acc, off, 64);
    if (lane < OUT2) out[(size_t)node * OUT2 + lane] = fmaf(acc, dinv[node], b2[lane]);
}

extern "C" void kernel_launch(void* const* d_in, const int* in_sizes, int n_in,
                              void* d_out, int out_size, void* d_ws, size_t ws_size,
                              hipStream_t stream) {
    const float* x  = (const float*)d_in[0];
    const int*   ei = (const int*)d_in[1];
    const float* W1 = (const float*)d_in[2];
    const float* b1 = (const float*)d_in[3];
    const float* W2 = (const float*)d_in[4];
    const float* b2 = (const float*)d_in[5];
    float* out = (float*)d_out;

    int N = in_sizes[0] / IN1;  // 50000
    int E = in_sizes[1] / 2;    // 800000
    const int* src = ei;
    const int* dst = ei + E;

    // ws: deg_i(N) | done(4) | cursor(N) | col(E) | dinv(N) | z(8N) | bsum(256)
    //     | xb(64N bf16)   total ~11.6 MB
    int* deg_i  = (int*)d_ws;
    int* done   = deg_i + N;
    int* cursor = done + 4;
    int* col    = cursor + N;
    float* dinv = (float*)(col + E);
    float* z    = dinv + N;
    int* bsum   = (int*)(z + (size_t)N * OUT2);
    unsigned short* xb = (unsigned short*)(bsum + 256);

    const int B = 256;
    int G = (N + B - 1) / B;  // 196 (must be <= 256)
    int E2 = E / 2;

    hipMemsetAsync(deg_i, 0, (size_t)(N + 4) * sizeof(int), stream);
    k_count<<<(E2 + B - 1) / B, B, 0, stream>>>(dst, deg_i, E2, E);
    k_scan_fused<<<G, B, 0, stream>>>(deg_i, x, cursor, dinv, xb, bsum, done, N, G);
    k_fill<<<(E2 + B - 1) / B, B, 0, stream>>>(src, dst, cursor, col, E2, E);

    k_node<<<(N + 15) / 16, 256, 0, stream>>>((const unsigned int*)xb, deg_i, cursor, col,
                                              dinv, W1, b1, W2, z, N);
    k_gather2<<<(N + 3) / 4, 256, 0, stream>>>(deg_i, cursor, col, z, dinv, b2, out, N);
}

// Round 8
// 230.862 us; speedup vs baseline: 1.0748x; 1.0748x over previous
//
#include <hip/hip_runtime.h>

#define IN1 64
#define MID 128
#define OUT2 8
#define YPAD 136

__device__ __forceinline__ unsigned short f2bf(float f) {
    unsigned int u = __float_as_uint(f);
    unsigned int r = (u + 0x7fff + ((u >> 16) & 1)) >> 16;  // RNE
    return (unsigned short)r;
}
__device__ __forceinline__ float bflo(unsigned int u) { return __uint_as_float(u << 16); }
__device__ __forceinline__ float bfhi(unsigned int u) { return __uint_as_float(u & 0xffff0000u); }

// ---------------- CSR build ----------------

__global__ void k_count(const int* __restrict__ dst, int* __restrict__ deg_i, int E4, int E) {
    int gid = blockIdx.x * blockDim.x + threadIdx.x;
    if (gid < E4) {
        int4 d = ((const int4*)dst)[gid];
        atomicAdd(&deg_i[d.x], 1);
        atomicAdd(&deg_i[d.y], 1);
        atomicAdd(&deg_i[d.z], 1);
        atomicAdd(&deg_i[d.w], 1);
    }
    if (gid == 0) {
        for (int e = E4 * 4; e < E; ++e) atomicAdd(&deg_i[dst[e]], 1);
    }
}

// deg -> dinv, global exclusive scan (publish + agent-scope spin; G<=256 blocks
// all co-resident), cursor, and bf16 prescale of x into xb.
__global__ __launch_bounds__(256) void k_scan_fused(const int* __restrict__ deg_i,
                                                    const float* __restrict__ x,
                                                    int* __restrict__ cursor,
                                                    float* __restrict__ dinv,
                                                    unsigned short* __restrict__ xb,
                                                    int* __restrict__ bsum,
                                                    int* __restrict__ done,
                                                    int n, int G) {
    __shared__ int wsum[4];
    __shared__ int wps[4];
    __shared__ float dloc[256];

    int t = threadIdx.x, b = blockIdx.x, i = b * 256 + t;
    int lane = t & 63, wid = t >> 6;

    int v = (i < n) ? deg_i[i] : 0;
    float di = rsqrtf((float)(v + 1));
    if (i < n) dinv[i] = di;
    dloc[t] = di;

    int s = v;
#pragma unroll
    for (int off = 1; off < 64; off <<= 1) {
        int u = __shfl_up(s, off, 64);
        if (lane >= off) s += u;
    }
    if (lane == 63) wsum[wid] = s;
    __syncthreads();
    int wprefix = 0;
    for (int w = 0; w < wid; ++w) wprefix += wsum[w];

    if (t == 0) {
        int tot = wsum[0] + wsum[1] + wsum[2] + wsum[3];
        __hip_atomic_store(&bsum[b], tot, __ATOMIC_RELEASE, __HIP_MEMORY_SCOPE_AGENT);
        __hip_atomic_fetch_add(done, 1, __ATOMIC_RELEASE, __HIP_MEMORY_SCOPE_AGENT);
    }

    // overlap the wait with the bf16 prescale of this block's 256 rows
    {
        const float4* x4 = (const float4*)x;
        int base4 = b * 4096;
        int lim4 = n * 16;
#pragma unroll 4
        for (int q = t; q < 4096; q += 256) {
            int g4 = base4 + q;
            if (g4 < lim4) {
                float d = dloc[q >> 4];
                float4 vx = x4[g4];
                ushort4 p;
                p.x = f2bf(vx.x * d); p.y = f2bf(vx.y * d);
                p.z = f2bf(vx.z * d); p.w = f2bf(vx.w * d);
                ((ushort4*)xb)[g4] = p;
            }
        }
    }

    if (t == 0) {
        while (__hip_atomic_load(done, __ATOMIC_ACQUIRE, __HIP_MEMORY_SCOPE_AGENT) < G) {}
    }
    __syncthreads();

    int pv = (t < b) ? __hip_atomic_load(&bsum[t], __ATOMIC_ACQUIRE, __HIP_MEMORY_SCOPE_AGENT) : 0;
    int ps = pv;
#pragma unroll
    for (int off = 1; off < 64; off <<= 1) ps += __shfl_xor(ps, off, 64);
    if (lane == 0) wps[wid] = ps;
    __syncthreads();
    int blockbase = wps[0] + wps[1] + wps[2] + wps[3];

    if (i < n) cursor[i] = (s - v) + wprefix + blockbase;
}

// col[p]=src via cursor atomics; afterwards cursor[d] = row end
__global__ void k_fill(const int* __restrict__ src, const int* __restrict__ dst,
                       int* __restrict__ cursor, int* __restrict__ col, int E4, int E) {
    int gid = blockIdx.x * blockDim.x + threadIdx.x;
    if (gid < E4) {
        int4 sv = ((const int4*)src)[gid];
        int4 dv = ((const int4*)dst)[gid];
        int p0 = atomicAdd(&cursor[dv.x], 1); col[p0] = sv.x;
        int p1 = atomicAdd(&cursor[dv.y], 1); col[p1] = sv.y;
        int p2 = atomicAdd(&cursor[dv.z], 1); col[p2] = sv.z;
        int p3 = atomicAdd(&cursor[dv.w], 1); col[p3] = sv.w;
    }
    if (gid == 0) {
        for (int e = E4 * 4; e < E; ++e) {
            int p = atomicAdd(&cursor[dst[e]], 1);
            col[p] = src[e];
        }
    }
}

// ---------------- fused layer1: bf16 gather + 64->128->8 MLP ----------------
// One wave = 4 nodes processed in PARALLEL by 16-lane groups.
// Group g (lanes g*16..g*16+15) owns node row0+g; lane fl2 owns feats 4*fl2..+3
// (one uint2 = 4 bf16 per row read). 4-deep neighbor unroll per group.
__global__ __launch_bounds__(256) void k_node(const uint2* __restrict__ xb2,
                                              const int* __restrict__ deg_i,
                                              const int* __restrict__ cursor,
                                              const int* __restrict__ col,
                                              const float* __restrict__ dinv,
                                              const float* __restrict__ W1,
                                              const float* __restrict__ b1,
                                              const float* __restrict__ W2,
                                              float* __restrict__ z, int n, int Etot) {
    __shared__ float w2s[MID * OUT2];   // [k][c]
    __shared__ float tS[4][4][IN1];     // wave-private
    __shared__ float yS[4][4][YPAD];    // wave-private

    int t = threadIdx.x;
    ((float4*)w2s)[t] = ((const float4*)W2)[t];

    int lane = t & 63, wave = t >> 6;
    int g = lane >> 4;        // group = node within quad
    int fl2 = lane & 15;      // 4-feat chunk index
    int q4 = fl2 & 3;
    int row0 = blockIdx.x * 16 + wave * 4;
    int row = row0 + g;
    bool valid = row < n;

    // ---- phase A: gather, 4 nodes in parallel ----
    float a0 = 0.f, a1 = 0.f, a2 = 0.f, a3 = 0.f;
    int j = 0, end = 0;
    if (valid) {
        end = cursor[row];
        j = end - deg_i[row];
        uint2 u = xb2[(size_t)row * 16 + fl2];  // self-loop
        a0 = bflo(u.x); a1 = bfhi(u.x); a2 = bflo(u.y); a3 = bfhi(u.y);
    }
    for (; j + 4 <= end; j += 4) {
        int cv = col[j + q4];
#pragma unroll
        for (int p = 0; p < 4; ++p) {
            int s = __shfl(cv, (g << 4) + p, 64);  // own-group lane: exec-safe
            uint2 u = xb2[(size_t)s * 16 + fl2];
            a0 += bflo(u.x); a1 += bfhi(u.x);
            a2 += bflo(u.y); a3 += bfhi(u.y);
        }
    }
    int rem = end - j;  // 0..3, uniform within group
    if (rem > 0) {
        int idx = j + q4;
        int cv = (q4 < rem) ? col[min(idx, Etot - 1)] : 0;
#pragma unroll
        for (int p = 0; p < 4; ++p) {
            int s = __shfl(cv, (g << 4) + p, 64);
            if (p < rem) {
                uint2 u = xb2[(size_t)s * 16 + fl2];
                a0 += bflo(u.x); a1 += bfhi(u.x);
                a2 += bflo(u.y); a3 += bfhi(u.y);
            }
        }
    }
    {
        float4 w = {a0, a1, a2, a3};
        *(float4*)&tS[wave][g][4 * fl2] = w;  // contiguous b128, conflict-free
    }
    // no barrier: tS wave-private, in-order LDS within wave

    float dnd[4];
#pragma unroll
    for (int k = 0; k < 4; ++k) dnd[k] = dinv[min(row0 + k, n - 1)];

    // ---- phase B: y = relu(di * (gather @ W1) + b1), 4-node register blocked ----
    float ya0 = 0.f, yb0 = 0.f, ya1 = 0.f, yb1 = 0.f;
    float ya2 = 0.f, yb2 = 0.f, ya3 = 0.f, yb3 = 0.f;
#pragma unroll 4
    for (int k4 = 0; k4 < IN1; k4 += 4) {
        float4 t0 = *(const float4*)&tS[wave][0][k4];
        float4 t1 = *(const float4*)&tS[wave][1][k4];
        float4 t2 = *(const float4*)&tS[wave][2][k4];
        float4 t3 = *(const float4*)&tS[wave][3][k4];
#pragma unroll
        for (int kk = 0; kk < 4; ++kk) {
            int k = k4 + kk;
            float wa = W1[k * MID + lane];
            float wb = W1[k * MID + lane + 64];
            float e0 = (&t0.x)[kk], e1 = (&t1.x)[kk], e2 = (&t2.x)[kk], e3 = (&t3.x)[kk];
            ya0 = fmaf(e0, wa, ya0); yb0 = fmaf(e0, wb, yb0);
            ya1 = fmaf(e1, wa, ya1); yb1 = fmaf(e1, wb, yb1);
            ya2 = fmaf(e2, wa, ya2); yb2 = fmaf(e2, wb, yb2);
            ya3 = fmaf(e3, wa, ya3); yb3 = fmaf(e3, wb, yb3);
        }
    }
    float bl = b1[lane], bh = b1[lane + 64];
    yS[wave][0][lane] = fmaxf(fmaf(ya0, dnd[0], bl), 0.f);
    yS[wave][0][lane + 64] = fmaxf(fmaf(yb0, dnd[0], bh), 0.f);
    yS[wave][1][lane] = fmaxf(fmaf(ya1, dnd[1], bl), 0.f);
    yS[wave][1][lane + 64] = fmaxf(fmaf(yb1, dnd[1], bh), 0.f);
    yS[wave][2][lane] = fmaxf(fmaf(ya2, dnd[2], bl), 0.f);
    yS[wave][2][lane + 64] = fmaxf(fmaf(yb2, dnd[2], bh), 0.f);
    yS[wave][3][lane] = fmaxf(fmaf(ya3, dnd[3], bl), 0.f);
    yS[wave][3][lane + 64] = fmaxf(fmaf(yb3, dnd[3], bh), 0.f);

    __syncthreads();  // w2s visibility only

    // ---- phase C: z = di * (y @ W2) ----
    int nd2 = lane >> 4, ch = lane & 15;
    float p[OUT2];
#pragma unroll
    for (int c = 0; c < OUT2; ++c) p[c] = 0.0f;
#pragma unroll
    for (int kk = 0; kk < 8; ++kk) {
        int k = kk * 16 + ch;
        float yk = yS[wave][nd2][k];
        float4 wlo = *(const float4*)&w2s[k * OUT2];
        float4 whi = *(const float4*)&w2s[k * OUT2 + 4];
        p[0] = fmaf(yk, wlo.x, p[0]); p[1] = fmaf(yk, wlo.y, p[1]);
        p[2] = fmaf(yk, wlo.z, p[2]); p[3] = fmaf(yk, wlo.w, p[3]);
        p[4] = fmaf(yk, whi.x, p[4]); p[5] = fmaf(yk, whi.y, p[5]);
        p[6] = fmaf(yk, whi.z, p[6]); p[7] = fmaf(yk, whi.w, p[7]);
    }
#pragma unroll
    for (int off = 1; off < 16; off <<= 1) {
#pragma unroll
        for (int c = 0; c < OUT2; ++c) p[c] += __shfl_xor(p[c], off, 64);
    }
    int rw = row0 + nd2;
    if (rw < n && ch < OUT2) {
        z[(size_t)rw * OUT2 + ch] = p[ch] * dinv[rw];
    }
}

// ---------------- layer2 gather ----------------
__global__ __launch_bounds__(256) void k_gather2(const int* __restrict__ deg_i,
                                                 const int* __restrict__ cursor,
                                                 const int* __restrict__ col,
                                                 const float* __restrict__ z,
                                                 const float* __restrict__ dinv,
                                                 const float* __restrict__ b2,
                                                 float* __restrict__ out, int n) {
    int t = threadIdx.x, lane = t & 63, wave = t >> 6;
    int node = blockIdx.x * 4 + wave;
    if (node >= n) return;
    int nb = lane >> 3, c = lane & 7;
    float acc = (nb == 0) ? z[(size_t)node * OUT2 + c] : 0.0f;  // self-loop
    int end = cursor[node];
    int j = end - deg_i[node] + nb;
    for (; j + 8 < end; j += 16) {
        int s0 = col[j], s1 = col[j + 8];
        float a0 = z[(size_t)s0 * OUT2 + c];
        float a1 = z[(size_t)s1 * OUT2 + c];
        acc += a0 + a1;
    }
    if (j < end) acc += z[(size_t)col[j] * OUT2 + c];
#pragma unroll
    for (int off = 8; off < 64; off <<= 1) acc += __shfl_xor(acc, off, 64);
    if (lane < OUT2) out[(size_t)node * OUT2 + lane] = fmaf(acc, dinv[node], b2[lane]);
}

extern "C" void kernel_launch(void* const* d_in, const int* in_sizes, int n_in,
                              void* d_out, int out_size, void* d_ws, size_t ws_size,
                              hipStream_t stream) {
    const float* x  = (const float*)d_in[0];
    const int*   ei = (const int*)d_in[1];
    const float* W1 = (const float*)d_in[2];
    const float* b1 = (const float*)d_in[3];
    const float* W2 = (const float*)d_in[4];
    const float* b2 = (const float*)d_in[5];
    float* out = (float*)d_out;

    int N = in_sizes[0] / IN1;  // 50000
    int E = in_sizes[1] / 2;    // 800000
    const int* src = ei;
    const int* dst = ei + E;

    // ws: deg_i(N) | done(4) | cursor(N) | col(E) | dinv(N) | z(8N) | bsum(256)
    //     | xb(64N bf16)   ~11.6 MB; xb offset is 16B-aligned (5401040 B)
    int* deg_i  = (int*)d_ws;
    int* done   = deg_i + N;
    int* cursor = done + 4;
    int* col    = cursor + N;
    float* dinv = (float*)(col + E);
    float* z    = dinv + N;
    int* bsum   = (int*)(z + (size_t)N * OUT2);
    unsigned short* xb = (unsigned short*)(bsum + 256);

    const int B = 256;
    int G = (N + B - 1) / B;  // 196 (must be <= 256)
    int E4 = E / 4;

    hipMemsetAsync(deg_i, 0, (size_t)(N + 4) * sizeof(int), stream);
    k_count<<<(E4 + B - 1) / B, B, 0, stream>>>(dst, deg_i, E4, E);
    k_scan_fused<<<G, B, 0, stream>>>(deg_i, x, cursor, dinv, xb, bsum, done, N, G);
    k_fill<<<(E4 + B - 1) / B, B, 0, stream>>>(src, dst, cursor, col, E4, E);

    k_node<<<(N + 15) / 16, 256, 0, stream>>>((const uint2*)xb, deg_i, cursor, col,
                                              dinv, W1, b1, W2, z, N, E);
    k_gather2<<<(N + 3) / 4, 256, 0, stream>>>(deg_i, cursor, col, z, dinv, b2, out, N);
}